// Round 1
// baseline (23887.030 us; speedup 1.0000x reference)
//
#include <hip/hip_runtime.h>
#include <stdint.h>

// Problem constants
#define BATCH   64
#define SEQ     1024
#define DIN     512
#define H4      512          // recurrent state size
#define NGATE   4
#define GROUPS  8            // one per XCD (heuristic)
#define WPG     32           // workgroups per group
#define NBLK    (GROUPS*WPG) // 256
#define JT      16           // h-dims per WG
#define BH      (BATCH*H4)   // 32768 elements in h buffer

typedef __attribute__((ext_vector_type(8))) __bf16 v8bf;
typedef __attribute__((ext_vector_type(4))) float  v4f;

__device__ __forceinline__ unsigned short f2bf(float f) {
    union { float f; unsigned int u; } cv; cv.f = f;
    unsigned int u = cv.u;
    return (unsigned short)((u + 0x7FFFu + ((u >> 16) & 1u)) >> 16);
}

// build a bf16x8 fragment from 8 consecutive floats (32B aligned)
__device__ __forceinline__ v8bf make_frag(const float* p) {
    const float4* q = (const float4*)p;
    float4 a = q[0], b = q[1];
    union { unsigned short u[8]; v8bf v; } t;
    t.u[0] = f2bf(a.x); t.u[1] = f2bf(a.y); t.u[2] = f2bf(a.z); t.u[3] = f2bf(a.w);
    t.u[4] = f2bf(b.x); t.u[5] = f2bf(b.y); t.u[6] = f2bf(b.z); t.u[7] = f2bf(b.w);
    return t.v;
}

__device__ __forceinline__ v8bf ld8bf(const unsigned short* p) {
    v8bf v;
    __builtin_memcpy(&v, p, 16);   // -> global_load_dwordx4
    return v;
}

__device__ __forceinline__ v4f mfma16(v8bf a, v8bf b, v4f c) {
    return __builtin_amdgcn_mfma_f32_16x16x32_bf16(a, b, c, 0, 0, 0);
}

__device__ __forceinline__ float fast_sigmoid(float x) { return 1.0f / (1.0f + __expf(-x)); }
__device__ __forceinline__ float fast_tanh(float x)    { return 1.0f - 2.0f / (__expf(2.0f * x) + 1.0f); }

// ---------------------------------------------------------------------------
// init: zero h double-buffer slot 0 and the sync flags (ws is poisoned 0xAA
// before every timed launch, so this must run every call).
// ---------------------------------------------------------------------------
__global__ void mc_init_kernel(unsigned int* hbuf0_u32, int* flags) {
    int idx = blockIdx.x * 256 + threadIdx.x;
    if (idx < BH / 2) {               // 32768 ushorts = 16384 u32
        hbuf0_u32[idx] = 0u;
    } else {
        int f = idx - BH / 2;
        if (f < NBLK) flags[f] = 0;
    }
}

// ---------------------------------------------------------------------------
// persistent fused LSTM kernel
//   grid = 256 WGs of 256 threads; group g = blockIdx%8 handles batches
//   [8g, 8g+8); rank r = blockIdx/8 owns h-dims j in [16r, 16r+16) and the
//   4 gate rows {j, 512+j, 1024+j, 1536+j} of Wi and Wh (bf16 frags in regs).
// ---------------------------------------------------------------------------
__global__ void __launch_bounds__(256, 1)
mc_lstm_kernel(const float* __restrict__ X,    // [B][S][512] fp32
               const float* __restrict__ Wi,   // [2048][512] fp32
               const float* __restrict__ Wh,   // [2048][512] fp32
               const float* __restrict__ bi,   // [2048]
               const float* __restrict__ bh,   // [2048]
               float* __restrict__ out,        // outputs | h_last | c_last
               unsigned short* __restrict__ Xbf,   // ws: [B][S][512] bf16
               unsigned short* __restrict__ hbuf,  // ws: [2][B][512] bf16
               int* __restrict__ flags)            // ws: [8][32]
{
    const int blk  = blockIdx.x;
    const int g    = blk & 7;        // group (one per XCD if round-robin)
    const int r    = blk >> 3;       // rank within group, 0..31
    const int tid  = threadIdx.x;
    const int wave = tid >> 6;       // wave index == gate index u (0..3)
    const int lane = tid & 63;
    const int quad = lane >> 4;      // k-block selector in MFMA frags
    const int n16  = lane & 15;      // column index in MFMA tiles
    const int bA   = g * 8 + (n16 & 7);  // batch row this lane feeds into A frags

    __shared__ float gbuf[NGATE][8][JT]; // gate exchange, 2 KB

    // ---- load weight fragments into registers (once) ----
    // B-frag for row-major [N][K] weights: lane n16 -> row, quad*8+j -> k
    const int row = wave * H4 + r * JT + n16;            // gate row in [0,2048)
    v8bf whf[16], wif[16];
    {
        const float* whrow = Wh + (size_t)row * DIN + quad * 8;
        const float* wirow = Wi + (size_t)row * DIN + quad * 8;
#pragma unroll
        for (int kb = 0; kb < 16; ++kb) {
            whf[kb] = make_frag(whrow + kb * 32);
            wif[kb] = make_frag(wirow + kb * 32);
        }
    }

    // ---- per-combine-thread state ----
    const int bl = tid >> 4;         // (valid when tid<128): local batch 0..7
    const int jl = tid & 15;
    const int j  = r * JT + jl;      // h-dim 0..511
    const int bg = g * 8 + (tid >> 4); // global batch (combine threads)
    float bias_u[NGATE];
#pragma unroll
    for (int u = 0; u < NGATE; ++u)
        bias_u[u] = bi[u * H4 + j] + bh[u * H4 + j];
    float c_state = 0.0f;

    // ---- convert this group's X slice to bf16 (t-range [32r, 32r+32)) ----
    {
        const int bg0 = g * 8;
        for (int b = 0; b < 8; ++b) {
            for (int dt = 0; dt < 32; ++dt) {
                int tt = r * 32 + dt;
                const float2* src = (const float2*)(X + ((size_t)(bg0 + b) * SEQ + tt) * DIN);
                unsigned int* dst = (unsigned int*)(Xbf + ((size_t)(bg0 + b) * SEQ + tt) * DIN);
                float2 v = src[tid];
                dst[tid] = (unsigned int)f2bf(v.x) | ((unsigned int)f2bf(v.y) << 16);
            }
        }
    }
    __builtin_amdgcn_fence(__ATOMIC_RELEASE, "agent");
    __syncthreads();
    if (tid == 0)
        __hip_atomic_store(&flags[g * WPG + r], 1, __ATOMIC_RELAXED, __HIP_MEMORY_SCOPE_AGENT);
    if (tid < WPG) {
        while (__hip_atomic_load(&flags[g * WPG + tid], __ATOMIC_RELAXED,
                                 __HIP_MEMORY_SCOPE_AGENT) < 1) {}
    }
    __syncthreads();
    __builtin_amdgcn_fence(__ATOMIC_ACQUIRE, "agent");

    // ---- precompute gates_x accumulator for t=0 ----
    v8bf xf[16];
    v4f gacc;
    {
        const unsigned short* xrow = Xbf + (size_t)bA * SEQ * DIN + quad * 8; // t=0
#pragma unroll
        for (int kb = 0; kb < 16; ++kb) xf[kb] = ld8bf(xrow + kb * 32);
        v4f a0 = (v4f){0.f, 0.f, 0.f, 0.f}, a1 = (v4f){0.f, 0.f, 0.f, 0.f};
#pragma unroll
        for (int kb = 0; kb < 16; kb += 2) {
            a0 = mfma16(xf[kb], wif[kb], a0);
            a1 = mfma16(xf[kb + 1], wif[kb + 1], a1);
        }
        gacc = a0 + a1;
    }

    const size_t hlast_off = (size_t)BATCH * SEQ * H4;
    const size_t clast_off = hlast_off + (size_t)BATCH * H4;

    // ============================ time loop ============================
    for (int t = 0; t < SEQ; ++t) {
        // 1) prefetch next-step X fragments (independent of the barrier)
        if (t + 1 < SEQ) {
            const unsigned short* xrow = Xbf + ((size_t)bA * SEQ + (t + 1)) * DIN + quad * 8;
#pragma unroll
            for (int kb = 0; kb < 16; ++kb) xf[kb] = ld8bf(xrow + kb * 32);
        }

        // 2) wait until all WGs of the group finished step t-1
        if (tid < WPG) {
            while (__hip_atomic_load(&flags[g * WPG + tid], __ATOMIC_RELAXED,
                                     __HIP_MEMORY_SCOPE_AGENT) < t + 1) {}
        }
        __syncthreads();
        __builtin_amdgcn_fence(__ATOMIC_ACQUIRE, "agent");

        // 3) load h fragments and run the Wh MFMA chain (acc starts at gates_x)
        {
            const unsigned short* hrow = hbuf + (size_t)(t & 1) * BH + (size_t)bA * H4 + quad * 8;
            v8bf hf[16];
#pragma unroll
            for (int kb = 0; kb < 16; ++kb) hf[kb] = ld8bf(hrow + kb * 32);
            v4f a0 = gacc, a1 = (v4f){0.f, 0.f, 0.f, 0.f};
#pragma unroll
            for (int kb = 0; kb < 16; kb += 2) {
                a0 = mfma16(hf[kb], whf[kb], a0);
                a1 = mfma16(hf[kb + 1], whf[kb + 1], a1);
            }
            v4f acc = a0 + a1;
            // write gates to LDS: D row = quad*4+reg = batch, col = n16 = jl
            if (quad < 2) {
#pragma unroll
                for (int v = 0; v < 4; ++v)
                    gbuf[wave][quad * 4 + v][n16] = acc[v];
            }
        }
        __syncthreads();

        // 4) LSTM combine for (batch bl, h-dim j): one thread each (tid<128)
        if (tid < 128) {
            float gi = gbuf[0][bl][jl] + bias_u[0];
            float gf = gbuf[1][bl][jl] + bias_u[1];
            float gg = gbuf[2][bl][jl] + bias_u[2];
            float go = gbuf[3][bl][jl] + bias_u[3];
            float si = fast_sigmoid(gi);
            float sf = fast_sigmoid(gf);
            float so = fast_sigmoid(go);
            float tg = fast_tanh(gg);
            c_state = sf * c_state + si * tg;
            float h = so * fast_tanh(c_state);
            out[((size_t)bg * SEQ + t) * H4 + j] = h;
            hbuf[(size_t)((t + 1) & 1) * BH + (size_t)bg * H4 + j] = f2bf(h);
            if (t == SEQ - 1) {
                out[hlast_off + (size_t)bg * H4 + j] = h;
                out[clast_off + (size_t)bg * H4 + j] = c_state;
            }
        }

        // 5) publish h_t, then announce completion of step t
        __builtin_amdgcn_fence(__ATOMIC_RELEASE, "agent");
        __syncthreads();
        if (tid == 0)
            __hip_atomic_store(&flags[g * WPG + r], t + 2, __ATOMIC_RELAXED,
                               __HIP_MEMORY_SCOPE_AGENT);

        // 6) off critical path: gates_x for t+1 from prefetched X frags
        if (t + 1 < SEQ) {
            v4f a0 = (v4f){0.f, 0.f, 0.f, 0.f}, a1 = (v4f){0.f, 0.f, 0.f, 0.f};
#pragma unroll
            for (int kb = 0; kb < 16; kb += 2) {
                a0 = mfma16(xf[kb], wif[kb], a0);
                a1 = mfma16(xf[kb + 1], wif[kb + 1], a1);
            }
            gacc = a0 + a1;
        }
    }
}

// ---------------------------------------------------------------------------
extern "C" void kernel_launch(void* const* d_in, const int* in_sizes, int n_in,
                              void* d_out, int out_size, void* d_ws, size_t ws_size,
                              hipStream_t stream) {
    const float* X  = (const float*)d_in[0];
    const float* Wi = (const float*)d_in[1];
    const float* Wh = (const float*)d_in[2];
    const float* bi = (const float*)d_in[3];
    const float* bh = (const float*)d_in[4];
    float* out = (float*)d_out;

    // ws layout: Xbf [B*S*512] bf16 | hbuf [2*B*512] bf16 | flags [256] int
    unsigned short* Xbf  = (unsigned short*)d_ws;
    unsigned short* hbuf = Xbf + (size_t)BATCH * SEQ * DIN;
    int* flags = (int*)(hbuf + (size_t)2 * BH);

    // zero hbuf slot 0 (16384 u32) + 256 flags = 16640 u32 -> 65 blocks x 256
    mc_init_kernel<<<65, 256, 0, stream>>>((unsigned int*)hbuf, flags);
    mc_lstm_kernel<<<NBLK, 256, 0, stream>>>(X, Wi, Wh, bi, bh, out, Xbf, hbuf, flags);
}

// Round 2
// 5814.679 us; speedup vs baseline: 4.1081x; 4.1081x over previous
//
#include <hip/hip_runtime.h>
#include <stdint.h>

// Problem constants
#define BATCH   64
#define SEQ     1024
#define DIN     512
#define H4      512          // recurrent state size
#define NG      2048         // gates
#define GROUPS  8            // batch groups of 8
#define WPG     16           // workgroups per group
#define NBLK    (GROUPS*WPG) // 128
#define JT      32           // h-dims per WG (2 N-tiles of 16)

typedef __attribute__((ext_vector_type(8))) __bf16 v8bf;
typedef __attribute__((ext_vector_type(4))) float  v4f;

__device__ __forceinline__ unsigned short f2bf(float f) {
    union { float f; unsigned int u; } cv; cv.f = f;
    unsigned int u = cv.u;
    return (unsigned short)((u + 0x7FFFu + ((u >> 16) & 1u)) >> 16);
}
__device__ __forceinline__ float bf2f(unsigned int b16) {
    union { unsigned int u; float f; } cv; cv.u = (b16 & 0xFFFFu) << 16; return cv.f;
}
// build a bf16x8 fragment from 8 consecutive fp32 (32B aligned)
__device__ __forceinline__ v8bf make_frag(const float* p) {
    const float4* q = (const float4*)p;
    float4 a = q[0], b = q[1];
    union { unsigned short u[8]; v8bf v; } t;
    t.u[0] = f2bf(a.x); t.u[1] = f2bf(a.y); t.u[2] = f2bf(a.z); t.u[3] = f2bf(a.w);
    t.u[4] = f2bf(b.x); t.u[5] = f2bf(b.y); t.u[6] = f2bf(b.z); t.u[7] = f2bf(b.w);
    return t.v;
}
__device__ __forceinline__ v4f mfma16(v8bf a, v8bf b, v4f c) {
    return __builtin_amdgcn_mfma_f32_16x16x32_bf16(a, b, c, 0, 0, 0);
}
__device__ __forceinline__ float fast_sigmoid(float x) { return 1.0f / (1.0f + __expf(-x)); }
__device__ __forceinline__ float fast_tanh(float x)    { return 1.0f - 2.0f / (__expf(2.0f * x) + 1.0f); }

// ---------------------------------------------------------------------------
// init: zero h slot 0 (bf16 [64][512] = 16384 u32) + 128 flags
// ---------------------------------------------------------------------------
__global__ void mc_init_kernel(unsigned int* hbuf_u32, int* flags) {
    int idx = blockIdx.x * 256 + threadIdx.x;
    if (idx < 16384) {
        hbuf_u32[idx] = 0u;
    } else if (idx - 16384 < NBLK) {
        flags[idx - 16384] = 0;
    }
}

// ---------------------------------------------------------------------------
// gemmx: gx[t][gate][batch] = sum_k X[batch][t][k] * Wi[gate][k]   (bf16 out)
// grid: 4096 WGs = (t-group of 8) x (gate-tile of 64); 4 waves x 16 gates.
// ---------------------------------------------------------------------------
__global__ void __launch_bounds__(256, 1)
mc_gemmx_kernel(const float* __restrict__ X,   // [64][1024][512]
                const float* __restrict__ Wi,  // [2048][512]
                unsigned short* __restrict__ gx) // [1024][2048][64] bf16
{
    const int blk = blockIdx.x;
    const int gt  = blk & 31;          // gate tile (64 gates)
    const int tg  = blk >> 5;          // t-group (8 steps)
    const int tid = threadIdx.x;
    const int u   = tid >> 6;          // wave
    const int lane = tid & 63;
    const int quad = lane >> 4;
    const int n16  = lane & 15;

    // A fragments: Wi rows (m = gate-local = n16, k = quad*8+j)
    const int grow = gt * 64 + u * 16 + n16;
    v8bf wf[16];
    {
        const float* wr = Wi + (size_t)grow * DIN + quad * 8;
#pragma unroll
        for (int kb = 0; kb < 16; ++kb) wf[kb] = make_frag(wr + kb * 32);
    }

    for (int tt = 0; tt < 8; ++tt) {
        const int t = tg * 8 + tt;
        v4f c[4];
#pragma unroll
        for (int bt = 0; bt < 4; ++bt) c[bt] = (v4f){0.f, 0.f, 0.f, 0.f};
#pragma unroll
        for (int kb = 0; kb < 16; ++kb) {
#pragma unroll
            for (int bt = 0; bt < 4; ++bt) {
                // B fragment: x[batch = bt*16+n16][t][kb*32 + quad*8 ..]
                v8bf xf = make_frag(X + ((size_t)(bt * 16 + n16) * SEQ + t) * DIN
                                      + kb * 32 + quad * 8);
                c[bt] = mfma16(wf[kb], xf, c[bt]);
            }
        }
        // C layout: row (quad*4+v) = gate-local, col n16 = batch-local
        const size_t base = ((size_t)t * NG + gt * 64 + u * 16) * BATCH;
#pragma unroll
        for (int bt = 0; bt < 4; ++bt) {
#pragma unroll
            for (int v = 0; v < 4; ++v)
                gx[base + (size_t)(quad * 4 + v) * BATCH + bt * 16 + n16] = f2bf(c[bt][v]);
        }
    }
}

// ---------------------------------------------------------------------------
// persistent LSTM scan. 128 WGs: group g = blk&7 (batches 8g..8g+8),
// rank r = blk>>3 owns h-dims [32r, 32r+32) and gate rows {u*512 + 32r + jl}.
// Cross-WG coherence: relaxed agent-scope atomics only (per-access sc1),
// NO fences -> L2 stays warm for gx stream / out writes.
// ---------------------------------------------------------------------------
__global__ void __launch_bounds__(256, 1)
mc_lstm_kernel(const float* __restrict__ Wh,   // [2048][512]
               const float* __restrict__ bi,   // [2048]
               const float* __restrict__ bh,   // [2048]
               float* __restrict__ out,        // outputs | h_last | c_last
               const unsigned short* __restrict__ gx,   // [1024][2048][64] bf16
               unsigned short* __restrict__ hbuf,       // [2][64][512] bf16
               int* __restrict__ flags)                 // [8][16]
{
    const int blk = blockIdx.x;
    const int g   = blk & 7;
    const int r   = blk >> 3;
    const int tid = threadIdx.x;
    const int u    = tid >> 6;      // wave = gate index
    const int lane = tid & 63;
    const int quad = lane >> 4;
    const int n16  = lane & 15;

    __shared__ unsigned short hlds[8][520];   // 8 batches x 512 dims, +8 pad
    __shared__ float gbuf[4][8][32];          // gate exchange

    // Wh B-fragments in registers: 2 N-tiles x 16 k-blocks
    v8bf whf[2][16];
#pragma unroll
    for (int nt = 0; nt < 2; ++nt) {
        const int row = u * H4 + r * JT + nt * 16 + n16;
        const float* wr = Wh + (size_t)row * DIN + quad * 8;
#pragma unroll
        for (int kb = 0; kb < 16; ++kb) whf[nt][kb] = make_frag(wr + kb * 32);
    }

    // combine-thread constants (all 256 threads combine)
    const int cb = tid >> 5;          // local batch 0..7
    const int cj = tid & 31;          // local h-dim 0..31
    const int j  = r * JT + cj;       // h-dim 0..511
    const int bg = g * 8 + cb;        // global batch
    float bias_u[4];
#pragma unroll
    for (int uu = 0; uu < 4; ++uu) bias_u[uu] = bi[uu * H4 + j] + bh[uu * H4 + j];
    float c_state = 0.0f;

    // gx prefetch base: 4 batches (quad&1)*4.. of gates u*512 + r*32 + nt*16 + n16
    const unsigned short* gx0 = gx + (size_t)(u * H4 + r * JT + n16) * BATCH
                                   + g * 8 + (quad & 1) * 4;
    unsigned long long gxp0 = *(const unsigned long long*)(gx0);
    unsigned long long gxp1 = *(const unsigned long long*)(gx0 + 16 * BATCH);

    int* myflags = flags + g * WPG;
    const size_t hlast = (size_t)BATCH * SEQ * H4;
    const size_t clast = hlast + (size_t)BATCH * H4;

    for (int t = 0; t < SEQ; ++t) {
        // 1) wait for all WGs of the group to have published h_t
        if (tid < WPG) {
            while (__hip_atomic_load(&myflags[tid], __ATOMIC_RELAXED,
                                     __HIP_MEMORY_SCOPE_AGENT) < t) {}
        }
        __syncthreads();

        // 2) cooperative coherent load of h_t (8 KB bf16) into LDS
        {
            const unsigned long long* hb = (const unsigned long long*)
                (hbuf + (size_t)(t & 1) * BATCH * H4 + (size_t)(g * 8 + cb) * H4);
#pragma unroll
            for (int k = 0; k < 4; ++k) {
                unsigned long long v = __hip_atomic_load(&hb[cj + 32 * k],
                        __ATOMIC_RELAXED, __HIP_MEMORY_SCOPE_AGENT);
                *(unsigned long long*)&hlds[cb][4 * cj + 128 * k] = v;
            }
        }
        __syncthreads();

        // 3) MFMA: gates = gx + h @ Wh^T  (C init from prefetched gx)
        {
            v4f acc0, acc1;
#pragma unroll
            for (int v = 0; v < 4; ++v) {
                acc0[v] = bf2f((unsigned int)(gxp0 >> (16 * v)));
                acc1[v] = bf2f((unsigned int)(gxp1 >> (16 * v)));
            }
#pragma unroll
            for (int kb = 0; kb < 16; ++kb) {
                v8bf hf;
                __builtin_memcpy(&hf, &hlds[n16 & 7][kb * 32 + quad * 8], 16);
                acc0 = mfma16(hf, whf[0][kb], acc0);
                acc1 = mfma16(hf, whf[1][kb], acc1);
            }
            if (quad < 2) {
#pragma unroll
                for (int v = 0; v < 4; ++v) {
                    gbuf[u][quad * 4 + v][n16]      = acc0[v];
                    gbuf[u][quad * 4 + v][16 + n16] = acc1[v];
                }
            }
        }
        __syncthreads();

        // 4) LSTM combine: one thread per (batch, h-dim)
        {
            float gi = gbuf[0][cb][cj] + bias_u[0];
            float gf = gbuf[1][cb][cj] + bias_u[1];
            float gg = gbuf[2][cb][cj] + bias_u[2];
            float go = gbuf[3][cb][cj] + bias_u[3];
            float si = fast_sigmoid(gi);
            float sf = fast_sigmoid(gf);
            float so = fast_sigmoid(go);
            float tg = fast_tanh(gg);
            c_state = sf * c_state + si * tg;
            float h = so * fast_tanh(c_state);
            out[((size_t)bg * SEQ + t) * H4 + j] = h;
            // pack bf16 pairs, publish h_{t+1} coherently
            float hn = __shfl_xor(h, 1);
            if ((tid & 1) == 0) {
                unsigned int pv = (unsigned int)f2bf(h) | ((unsigned int)f2bf(hn) << 16);
                unsigned int* dst = (unsigned int*)
                    (hbuf + (size_t)((t + 1) & 1) * BATCH * H4 + (size_t)bg * H4 + j);
                __hip_atomic_store(dst, pv, __ATOMIC_RELAXED, __HIP_MEMORY_SCOPE_AGENT);
            }
            if (t == SEQ - 1) {
                out[hlast + (size_t)bg * H4 + j] = h;
                out[clast + (size_t)bg * H4 + j] = c_state;
            }
        }

        // 5) drain own stores, then announce completion of step t
        asm volatile("s_waitcnt vmcnt(0)" ::: "memory");
        __syncthreads();
        if (tid == 0)
            __hip_atomic_store(&myflags[r], t + 1, __ATOMIC_RELAXED,
                               __HIP_MEMORY_SCOPE_AGENT);

        // 6) off critical path: prefetch gx for t+1
        if (t + 1 < SEQ) {
            const unsigned short* p = gx0 + (size_t)(t + 1) * NG * BATCH;
            gxp0 = *(const unsigned long long*)(p);
            gxp1 = *(const unsigned long long*)(p + 16 * BATCH);
        }
    }
}

// ---------------------------------------------------------------------------
extern "C" void kernel_launch(void* const* d_in, const int* in_sizes, int n_in,
                              void* d_out, int out_size, void* d_ws, size_t ws_size,
                              hipStream_t stream) {
    const float* X  = (const float*)d_in[0];
    const float* Wi = (const float*)d_in[1];
    const float* Wh = (const float*)d_in[2];
    const float* bi = (const float*)d_in[3];
    const float* bh = (const float*)d_in[4];
    float* out = (float*)d_out;

    // ws layout: gx bf16 [1024][2048][64] (256 MB) | hbuf bf16 [2][64][512] | flags[128]
    unsigned short* gxw  = (unsigned short*)d_ws;
    unsigned short* hbuf = gxw + (size_t)SEQ * NG * BATCH;
    int* flags = (int*)(hbuf + (size_t)2 * BATCH * H4);

    mc_init_kernel<<<65, 256, 0, stream>>>((unsigned int*)hbuf, flags);
    mc_gemmx_kernel<<<4096, 256, 0, stream>>>(X, Wi, gxw);
    mc_lstm_kernel<<<NBLK, 256, 0, stream>>>(Wh, bi, bh, out, gxw, hbuf, flags);
}

// Round 3
// 3652.592 us; speedup vs baseline: 6.5397x; 1.5919x over previous
//
#include <hip/hip_runtime.h>
#include <stdint.h>

// Problem constants
#define BATCH   64
#define SEQ     1024
#define DIN     512
#define H4      512          // recurrent state size
#define NG      2048         // gates
#define GROUPS  8
#define WPG     16
#define NBLK    (GROUPS*WPG) // 128
#define JT      32           // h-dims per lstm WG

typedef __attribute__((ext_vector_type(8))) __bf16 v8bf;
typedef __attribute__((ext_vector_type(4))) float  v4f;
typedef unsigned long long u64;
typedef unsigned int       u32;

__device__ __forceinline__ unsigned short f2bf(float f) {
    union { float f; u32 u; } cv; cv.f = f;
    u32 u = cv.u;
    return (unsigned short)((u + 0x7FFFu + ((u >> 16) & 1u)) >> 16);
}
__device__ __forceinline__ float bf2f(u32 b16) {
    union { u32 u; float f; } cv; cv.u = (b16 & 0xFFFFu) << 16; return cv.f;
}
__device__ __forceinline__ v8bf make_frag(const float* p) {
    const float4* q = (const float4*)p;
    float4 a = q[0], b = q[1];
    union { unsigned short u[8]; v8bf v; } t;
    t.u[0] = f2bf(a.x); t.u[1] = f2bf(a.y); t.u[2] = f2bf(a.z); t.u[3] = f2bf(a.w);
    t.u[4] = f2bf(b.x); t.u[5] = f2bf(b.y); t.u[6] = f2bf(b.z); t.u[7] = f2bf(b.w);
    return t.v;
}
__device__ __forceinline__ v4f mfma16(v8bf a, v8bf b, v4f c) {
    return __builtin_amdgcn_mfma_f32_16x16x32_bf16(a, b, c, 0, 0, 0);
}
__device__ __forceinline__ float fast_sigmoid(float x) { return 1.0f / (1.0f + __expf(-x)); }
__device__ __forceinline__ float fast_tanh(float x)    { return 1.0f - 2.0f / (__expf(2.0f * x) + 1.0f); }

// ---------------------------------------------------------------------------
// prep: zero hcomm parity-0 buffer (h_0 = 0 with tag 0). Buffer 1 keeps the
// 0xAAAAAAAA poison tag, which never equals a real tag (0..1024).
// ---------------------------------------------------------------------------
__global__ void mc_prep_kernel(u64* hcomm) {
    int idx = blockIdx.x * 256 + threadIdx.x;
    if (idx < BATCH * 256) hcomm[idx] = 0ull;
}

// ---------------------------------------------------------------------------
// gemmx: gx[t][grp][gate][8] = bf16( X[b][t][:] . Wi[gate][:] )
// grid 2048 = 128 t-octets x 16 gate-tiles(128 gates). X_t staged in LDS as
// bf16 with 16B-block XOR swizzle (conflict-free reads); Wi frags in regs.
// ---------------------------------------------------------------------------
__global__ void __launch_bounds__(256, 1)
mc_gemmx_kernel(const float* __restrict__ X,   // [64][1024][512]
                const float* __restrict__ Wi,  // [2048][512]
                unsigned short* __restrict__ gx)
{
    const int gt  = blockIdx.x & 15;   // gate tile (128 gates)
    const int tg  = blockIdx.x >> 4;   // t-octet
    const int tid = threadIdx.x;
    const int u    = tid >> 6;
    const int lane = tid & 63;
    const int quad = lane >> 4;
    const int n16  = lane & 15;

    __shared__ unsigned short xlds[64][512];   // 64 KB

    // Wi fragments: 2 gate-subtiles of 64 (wave covers 16 gates each)
    v8bf wf[2][16];
#pragma unroll
    for (int w2 = 0; w2 < 2; ++w2) {
        const int grow = gt * 128 + w2 * 64 + u * 16 + n16;
        const float* wr = Wi + (size_t)grow * DIN + quad * 8;
#pragma unroll
        for (int kb = 0; kb < 16; ++kb) wf[w2][kb] = make_frag(wr + kb * 32);
    }

    const int sb = tid >> 2;   // staging batch
    const int sq = tid & 3;    // staging quarter (128 elems)

    for (int tt = 0; tt < 8; ++tt) {
        const int t = tg * 8 + tt;
        __syncthreads();
        // stage X_t -> LDS bf16 (swizzled 16B blocks)
        {
            const float* xs = X + ((size_t)sb * SEQ + t) * DIN + sq * 128;
#pragma unroll
            for (int i = 0; i < 16; ++i) {
                const int c = sq * 16 + i;
                float4 a = ((const float4*)xs)[2 * i];
                float4 b = ((const float4*)xs)[2 * i + 1];
                uint4 pk;
                pk.x = (u32)f2bf(a.x) | ((u32)f2bf(a.y) << 16);
                pk.y = (u32)f2bf(a.z) | ((u32)f2bf(a.w) << 16);
                pk.z = (u32)f2bf(b.x) | ((u32)f2bf(b.y) << 16);
                pk.w = (u32)f2bf(b.z) | ((u32)f2bf(b.w) << 16);
                *(uint4*)&xlds[sb][(c ^ (sb & 7)) * 8] = pk;
            }
        }
        __syncthreads();

        v4f acc[2][4];
#pragma unroll
        for (int w2 = 0; w2 < 2; ++w2)
#pragma unroll
            for (int bt = 0; bt < 4; ++bt) acc[w2][bt] = (v4f){0.f, 0.f, 0.f, 0.f};

#pragma unroll
        for (int kb = 0; kb < 16; ++kb) {
#pragma unroll
            for (int bt = 0; bt < 4; ++bt) {
                const int b = bt * 16 + n16;
                v8bf xf;
                __builtin_memcpy(&xf, &xlds[b][((kb * 4 + quad) ^ (b & 7)) * 8], 16);
                acc[0][bt] = mfma16(wf[0][kb], xf, acc[0][bt]);
                acc[1][bt] = mfma16(wf[1][kb], xf, acc[1][bt]);
            }
        }

        // store: D row (quad*4+v) = gate-local, col n16 = batch-local
        const size_t tb = (size_t)t * (8 * NG * 8);
#pragma unroll
        for (int w2 = 0; w2 < 2; ++w2) {
            const int gate = gt * 128 + w2 * 64 + u * 16 + quad * 4;
#pragma unroll
            for (int bt = 0; bt < 4; ++bt) {
                const int batch = bt * 16 + n16;
                unsigned short* dst = gx + tb + (size_t)(batch >> 3) * (NG * 8)
                                    + (size_t)gate * 8 + (batch & 7);
#pragma unroll
                for (int v = 0; v < 4; ++v) dst[(size_t)v * 8] = f2bf(acc[w2][bt][v]);
            }
        }
    }
}

// ---------------------------------------------------------------------------
// persistent LSTM scan, single-hop tagged-h exchange.
// 128 WGs: group g = blk&7 (batches 8g..8g+8), rank r = blk>>3 owns h-dims
// [32r,32r+32). hcomm word = {hi32: epoch tag, lo32: bf16 h-pair}; pollers
// spin on the data words directly (tag == t) -> one global hop per step.
// ---------------------------------------------------------------------------
__global__ void __launch_bounds__(256, 1)
mc_lstm_kernel(const float* __restrict__ Wh,   // [2048][512]
               const float* __restrict__ bi,   // [2048]
               const float* __restrict__ bh,   // [2048]
               float* __restrict__ out,        // outputs | h_last | c_last
               const unsigned short* __restrict__ gx,  // [1024][8][2048][8] bf16
               u64* __restrict__ hcomm)                // [2][64][256] tagged words
{
    const int blk = blockIdx.x;
    const int g   = blk & 7;
    const int r   = blk >> 3;
    const int tid = threadIdx.x;
    const int u    = tid >> 6;      // wave = gate index
    const int lane = tid & 63;
    const int quad = lane >> 4;
    const int n16  = lane & 15;

    __shared__ unsigned short hlds[8][520];
    __shared__ float gbuf[4][8][32];

    // Wh B-fragments: 2 N-tiles x 16 k-blocks (128 VGPRs)
    v8bf whf[2][16];
#pragma unroll
    for (int nt = 0; nt < 2; ++nt) {
        const int row = u * H4 + r * JT + nt * 16 + n16;
        const float* wr = Wh + (size_t)row * DIN + quad * 8;
#pragma unroll
        for (int kb = 0; kb < 16; ++kb) whf[nt][kb] = make_frag(wr + kb * 32);
    }

    const int cb = tid >> 5;          // local batch 0..7
    const int cj = tid & 31;          // local h-dim 0..31
    const int j  = r * JT + cj;
    const int bg = g * 8 + cb;        // global batch
    float bias_u[4];
#pragma unroll
    for (int uu = 0; uu < 4; ++uu) bias_u[uu] = bi[uu * H4 + j] + bh[uu * H4 + j];
    float c_state = 0.0f;

    // poll slice: batch bg, dim-pairs [8cj, 8cj+8) -> dims [16cj, 16cj+16)
    u64* psrc = hcomm + (size_t)bg * 256 + cj * 8;

    // gx lane pointer: gates u*512 + r*32 + {n16, 16+n16}, batches (quad&1)*4..
    const unsigned short* gxlane = gx + (size_t)g * (NG * 8)
                                 + (size_t)(u * H4 + r * JT + n16) * 8 + (quad & 1) * 4;
    u64 gxp0 = *(const u64*)(gxlane);
    u64 gxp1 = *(const u64*)(gxlane + 128);

    const size_t hlast = (size_t)BATCH * SEQ * H4;
    const size_t clast = hlast + (size_t)BATCH * H4;

    for (int t = 0; t < SEQ; ++t) {
        // 1) poll tagged h_t words (single hop: tag + data in one 8B load)
        {
            u64* ps = psrc + (size_t)(t & 1) * (BATCH * 256);
            u64 w[8];
#pragma unroll
            for (int i = 0; i < 8; ++i)
                w[i] = __hip_atomic_load(&ps[i], __ATOMIC_RELAXED, __HIP_MEMORY_SCOPE_AGENT);
            bool pending = true;
            while (pending) {
                pending = false;
#pragma unroll
                for (int i = 0; i < 8; ++i) {
                    if ((u32)(w[i] >> 32) != (u32)t) {
                        w[i] = __hip_atomic_load(&ps[i], __ATOMIC_RELAXED,
                                                 __HIP_MEMORY_SCOPE_AGENT);
                        pending = true;
                    }
                }
            }
            u32 lo[8];
#pragma unroll
            for (int i = 0; i < 8; ++i) lo[i] = (u32)w[i];
            __builtin_memcpy(&hlds[cb][16 * cj], lo, 32);
        }
        __syncthreads();

        // 2) MFMA: gates = gx + h @ Wh^T
        {
            v4f acc0, acc1;
#pragma unroll
            for (int v = 0; v < 4; ++v) {
                acc0[v] = bf2f((u32)(gxp0 >> (16 * v)));
                acc1[v] = bf2f((u32)(gxp1 >> (16 * v)));
            }
#pragma unroll
            for (int kb = 0; kb < 16; ++kb) {
                v8bf hf;
                __builtin_memcpy(&hf, &hlds[n16 & 7][kb * 32 + quad * 8], 16);
                acc0 = mfma16(hf, whf[0][kb], acc0);
                acc1 = mfma16(hf, whf[1][kb], acc1);
            }
            if (quad < 2) {
#pragma unroll
                for (int v = 0; v < 4; ++v) {
                    gbuf[u][quad * 4 + v][n16]      = acc0[v];
                    gbuf[u][quad * 4 + v][16 + n16] = acc1[v];
                }
            }
        }
        __syncthreads();

        // 3) LSTM combine + tagged publish of h_{t+1}
        {
            float gi = gbuf[0][cb][cj] + bias_u[0];
            float gf = gbuf[1][cb][cj] + bias_u[1];
            float gg = gbuf[2][cb][cj] + bias_u[2];
            float go = gbuf[3][cb][cj] + bias_u[3];
            float si = fast_sigmoid(gi);
            float sf = fast_sigmoid(gf);
            float so = fast_sigmoid(go);
            float tg = fast_tanh(gg);
            c_state = sf * c_state + si * tg;
            float h = so * fast_tanh(c_state);
            out[((size_t)bg * SEQ + t) * H4 + j] = h;
            float hn = __shfl_xor(h, 1);
            if ((tid & 1) == 0) {
                u32 pv = (u32)f2bf(h) | ((u32)f2bf(hn) << 16);
                u64 word = ((u64)(u32)(t + 1) << 32) | (u64)pv;
                __hip_atomic_store(hcomm + (size_t)((t + 1) & 1) * (BATCH * 256)
                                       + (size_t)bg * 256 + (j >> 1),
                                   word, __ATOMIC_RELAXED, __HIP_MEMORY_SCOPE_AGENT);
            }
            if (t == SEQ - 1) {
                out[hlast + (size_t)bg * H4 + j] = h;
                out[clast + (size_t)bg * H4 + j] = c_state;
            }
        }
        __syncthreads();

        // 4) off critical path: prefetch gx for t+1
        if (t + 1 < SEQ) {
            const unsigned short* p = gxlane + (size_t)(t + 1) * (8 * NG * 8);
            gxp0 = *(const u64*)p;
            gxp1 = *(const u64*)(p + 128);
        }
    }
}

// ---------------------------------------------------------------------------
extern "C" void kernel_launch(void* const* d_in, const int* in_sizes, int n_in,
                              void* d_out, int out_size, void* d_ws, size_t ws_size,
                              hipStream_t stream) {
    const float* X  = (const float*)d_in[0];
    const float* Wi = (const float*)d_in[1];
    const float* Wh = (const float*)d_in[2];
    const float* bi = (const float*)d_in[3];
    const float* bh = (const float*)d_in[4];
    float* out = (float*)d_out;

    // ws: gx bf16 [1024][8][2048][8] (256 MB) | hcomm u64 [2][64][256] (256 KB)
    unsigned short* gxw = (unsigned short*)d_ws;
    u64* hcomm = (u64*)(gxw + (size_t)SEQ * NG * BATCH);

    mc_prep_kernel<<<64, 256, 0, stream>>>(hcomm);
    mc_gemmx_kernel<<<2048, 256, 0, stream>>>(X, Wi, gxw);
    mc_lstm_kernel<<<NBLK, 256, 0, stream>>>(Wh, bi, bh, out, gxw, hcomm);
}